// Round 6
// baseline (385.560 us; speedup 1.0000x reference)
//
#include <hip/hip_runtime.h>

typedef unsigned short u16;
typedef short bf16x8 __attribute__((ext_vector_type(8)));
typedef float f32x4 __attribute__((ext_vector_type(4)));
typedef unsigned short u16x8 __attribute__((ext_vector_type(8)));

#define B_DIM 64
#define C_DIM 2048
#define P_DIM 196
#define K_DIM 512
#define HS_DIM 1024

static __device__ __forceinline__ u16 f2bf(float f) {
    union { float f; unsigned u; } v; v.f = f;
    unsigned r = v.u + 0x7FFF + ((v.u >> 16) & 1);
    return (u16)(r >> 16);
}

static __device__ __forceinline__ float bf2f(u16 b) {
    union { unsigned u; float f; } v; v.u = ((unsigned)b) << 16;
    return v.f;
}

static __device__ __forceinline__ float fast_tanh(float a) {
    float e = __expf(2.f * a);
    return 1.f - 2.f / (e + 1.f);
}

// ---------------- K1: per-(b,c) row stats -> ic = mean(x / max(||x||,eps)) ----
__global__ void k1_rowstats(const float* __restrict__ x, float* __restrict__ ic) {
    int row = blockIdx.x * 4 + (threadIdx.x >> 6);  // [0, B*C)
    int l = threadIdx.x & 63;
    const float* r = x + (size_t)row * P_DIM;
    float a0 = r[l], a1 = r[64 + l], a2 = r[128 + l];
    float a3 = (l < 4) ? r[192 + l] : 0.f;
    float s = a0 + a1 + a2 + a3;
    float q = a0 * a0 + a1 * a1 + a2 * a2 + a3 * a3;
    for (int off = 32; off; off >>= 1) { s += __shfl_down(s, off); q += __shfl_down(q, off); }
    if (l == 0) {
        float n = fmaxf(sqrtf(q), 1e-12f);
        ic[row] = s / ((float)P_DIM * n);
    }
}

// ---------------- K2: u[b,k] = bc[k]+whc[k,:]@h[b,:],  v[b,k] = bs[k]+whs[k,:]@h[b,:]
__global__ __launch_bounds__(256) void k2_hproj(
    const float* __restrict__ h, const float* __restrict__ whc,
    const float* __restrict__ bc, const float* __restrict__ whs,
    const float* __restrict__ bs, float* __restrict__ u, float* __restrict__ v) {
    __shared__ float rc[1024], rs[1024];
    int k = blockIdx.x;
    int t = threadIdx.x, w = t >> 6, l = t & 63;
    for (int i = t; i < 1024; i += 256) {
        rc[i] = whc[(size_t)k * HS_DIM + i];
        rs[i] = whs[(size_t)k * HS_DIM + i];
    }
    __syncthreads();
    float bcv = bc[k], bsv = bs[k];
    for (int bb = 0; bb < 16; ++bb) {
        int b = (w << 4) + bb;
        const float* hr = h + (size_t)b * HS_DIM;
        float su = 0.f, sv = 0.f;
        #pragma unroll
        for (int j = 0; j < 16; ++j) {
            float hv = hr[l + (j << 6)];
            su = fmaf(rc[l + (j << 6)], hv, su);
            sv = fmaf(rs[l + (j << 6)], hv, sv);
        }
        #pragma unroll
        for (int off = 32; off; off >>= 1) { su += __shfl_down(su, off); sv += __shfl_down(sv, off); }
        if (l == 0) { u[b * K_DIM + k] = su + bcv; v[b * K_DIM + k] = sv + bsv; }
    }
}

// ---------------- K2b: repack ws f32[512][2048] -> fragment-native bf16 ----
__global__ void k2b_conv(const float* __restrict__ ws, u16* __restrict__ wsb2) {
    int i = blockIdx.x * 256 + threadIdx.x;   // 131072 chunks
    int lane = i & 63;
    int kb = (i >> 6) & 31;
    int cstep = i >> 11;
    int r = kb * 16 + (lane & 15);
    int c0 = (cstep << 5) + ((lane >> 4) << 3);
    const float* src = ws + (size_t)r * C_DIM + c0;
    float4 f0 = *(const float4*)(src);
    float4 f1 = *(const float4*)(src + 4);
    u16x8 o;
    o[0] = f2bf(f0.x); o[1] = f2bf(f0.y); o[2] = f2bf(f0.z); o[3] = f2bf(f0.w);
    o[4] = f2bf(f1.x); o[5] = f2bf(f1.y); o[6] = f2bf(f1.z); o[7] = f2bf(f1.w);
    *(u16x8*)(wsb2 + (size_t)i * 8) = o;
}

// ---------------- K3: sc[b,c] = sum_k wci[k]*tanh(wc[k]*ic[b,c]+u[b,k]) + bci --
__global__ void k3_sc(const float* __restrict__ ic, const float* __restrict__ u,
                      const float* __restrict__ wc, const float* __restrict__ wci,
                      const float* __restrict__ bci, float* __restrict__ sc) {
    __shared__ float swc[512], swci[512], su[512];
    int b = blockIdx.y;
    int c = blockIdx.x * 256 + threadIdx.x;
    for (int i = threadIdx.x; i < 512; i += 256) {
        swc[i] = wc[i]; swci[i] = wci[i]; su[i] = u[b * 512 + i];
    }
    __syncthreads();
    float icv = ic[(size_t)b * C_DIM + c];
    float s = 0.f;
    #pragma unroll 8
    for (int k = 0; k < 512; k++) {
        float a = fmaf(swc[k], icv, su[k]);
        s = fmaf(swci[k], fast_tanh(a), s);
    }
    sc[(size_t)b * C_DIM + c] = s + bci[0];
}

// ---------------- K4: softmax over C -> ac; also zeroes cnsq[b,:] ----------------
__global__ void k4_softmax_c(const float* __restrict__ sc, float* __restrict__ ac,
                             float* __restrict__ cnsq) {
    int b = blockIdx.x, t = threadIdx.x;
    __shared__ float red[4], red2[4];
    if (t < P_DIM) cnsq[b * P_DIM + t] = 0.f;   // zero for k_xw's atomics
    const float* s = sc + (size_t)b * C_DIM;
    float vals[8]; float m = -1e30f;
    #pragma unroll
    for (int i = 0; i < 8; i++) { vals[i] = s[t + i * 256]; m = fmaxf(m, vals[i]); }
    for (int off = 32; off; off >>= 1) m = fmaxf(m, __shfl_xor(m, off));
    if ((t & 63) == 0) red[t >> 6] = m;
    __syncthreads();
    m = fmaxf(fmaxf(red[0], red[1]), fmaxf(red[2], red[3]));
    float sum = 0.f;
    #pragma unroll
    for (int i = 0; i < 8; i++) { vals[i] = __expf(vals[i] - m); sum += vals[i]; }
    for (int off = 32; off; off >>= 1) sum += __shfl_xor(sum, off);
    if ((t & 63) == 0) red2[t >> 6] = sum;
    __syncthreads();
    sum = red2[0] + red2[1] + red2[2] + red2[3];
    float inv = 1.f / sum;
    float* a = ac + (size_t)b * C_DIM;
    #pragma unroll
    for (int i = 0; i < 8; i++) a[t + i * 256] = vals[i] * inv;
}

// ---------------- K_XW: xw = bf16(x*ac); cnsq[b,p] += sum_c xw^2 ----------------
// grid (16 cchunks, 64 b), 256 thr; each wave 32 c-rows.
__global__ __launch_bounds__(256) void k_xw(
    const float* __restrict__ x, const float* __restrict__ ac,
    u16* __restrict__ xw, float* __restrict__ cnsq) {
    __shared__ float psq[4][200];
    int b = blockIdx.y;
    int c0 = blockIdx.x * 128 + (threadIdx.x >> 6) * 32;
    int w = threadIdx.x >> 6, l = threadIdx.x & 63;
    const float* xb = x + ((size_t)b * C_DIM + c0) * P_DIM;
    u16* xwb = xw + ((size_t)b * C_DIM + c0) * P_DIM;
    const float* acb = ac + (size_t)b * C_DIM + c0;
    float q0 = 0.f, q1 = 0.f, q2 = 0.f, q3 = 0.f;
    for (int i = 0; i < 32; ++i) {
        const float* r = xb + (size_t)i * P_DIM;
        float a = acb[i];
        float v0 = r[l] * a, v1 = r[64 + l] * a, v2 = r[128 + l] * a;
        float v3 = (l < 4) ? r[192 + l] * a : 0.f;
        q0 = fmaf(v0, v0, q0); q1 = fmaf(v1, v1, q1);
        q2 = fmaf(v2, v2, q2); q3 = fmaf(v3, v3, q3);
        u16* o = xwb + (size_t)i * P_DIM;
        o[l] = f2bf(v0); o[64 + l] = f2bf(v1); o[128 + l] = f2bf(v2);
        if (l < 4) o[192 + l] = f2bf(v3);
    }
    psq[w][l] = q0; psq[w][64 + l] = q1; psq[w][128 + l] = q2;
    if (l < 4) psq[w][192 + l] = q3;
    __syncthreads();
    int t = threadIdx.x;
    if (t < P_DIM) {
        float s = psq[0][t] + psq[1][t] + psq[2][t] + psq[3][t];
        atomicAdd(cnsq + b * P_DIM + t, s);
    }
}

// ---------------- K5: fused GEMM (ws@xw) + tanh + k-reduce -> ssp ----
// grid (4 ptiles, 2 ksplit, 64 b), 256 thr (4 waves).
// A: fragment-native repacked global -> regs, 2-step prefetch, 4 rotating sets.
// B: xw bf16 -> swizzled LDS transpose, double-buffered, 2-step-ahead regs.
__global__ __launch_bounds__(256, 2) void k5_gemm(
    const u16* __restrict__ xw, const u16* __restrict__ wsb2,
    const float* __restrict__ cnsq, const float* __restrict__ vv,
    const float* __restrict__ wsi, float* __restrict__ ssp) {
    __shared__ __align__(16) u16 lB[2][64 * 32];
    __shared__ float lss[4][64];

    const int p0 = blockIdx.x * 64;
    const int Rb = blockIdx.y * 256;
    const int b  = blockIdx.z;
    const int t = threadIdx.x;
    const int w = t >> 6, l = t & 63;
    const int lr16 = l & 15, lh = l >> 4;
    const int pg = l;
    const int co = w << 3;
    const int pp = p0 + pg;
    const bool pvld = pp < P_DIM;
    const int sBw = (pg >> 1) & 3;

    f32x4 acc[4][4];
    #pragma unroll
    for (int i = 0; i < 4; i++)
        #pragma unroll
        for (int j = 0; j < 4; j++)
            acc[i][j] = (f32x4){0.f, 0.f, 0.f, 0.f};

    const u16* xcol = xw + (size_t)b * (C_DIM * P_DIM) + pp;
    const bf16x8* abase = (const bf16x8*)wsb2 + ((Rb >> 4) + (w << 2)) * 64 + l;

    u16 xv[2][8];
    bf16x8 af[4][4];

    auto LOADX = [&](int step, int xs) {
        const int cc = (step << 5) + co;
        #pragma unroll
        for (int j = 0; j < 8; ++j)
            xv[xs][j] = pvld ? xcol[(size_t)(cc + j) * P_DIM] : (u16)0;
    };
    auto LOADA = [&](int step, int as_) {
        const bf16x8* p = abase + (size_t)step * 2048;
        #pragma unroll
        for (int mt = 0; mt < 4; ++mt) af[as_][mt] = p[mt * 64];
    };
    auto PROCB = [&](int xs, int bufi) {
        u16x8 pk;
        #pragma unroll
        for (int j = 0; j < 8; ++j) pk[j] = xv[xs][j];
        *(u16x8*)&lB[bufi][(pg << 5) + ((w ^ sBw) << 3)] = pk;
    };
    auto RD_B = [&](int bufi, bf16x8* bfr) {
        #pragma unroll
        for (int nt = 0; nt < 4; ++nt) {
            int r = (nt << 4) + lr16;
            int s = (r >> 1) & 3;
            bfr[nt] = *(const bf16x8*)&lB[bufi][(r << 5) + ((lh ^ s) << 3)];
        }
    };
    auto MFMA16 = [&](int as_, const bf16x8* bfr) {
        __builtin_amdgcn_s_setprio(1);
        #pragma unroll
        for (int mt = 0; mt < 4; ++mt)
            #pragma unroll
            for (int nt = 0; nt < 4; ++nt)
                acc[mt][nt] = __builtin_amdgcn_mfma_f32_16x16x32_bf16(
                    af[as_][mt], bfr[nt], acc[mt][nt], 0, 0, 0);
        __builtin_amdgcn_s_setprio(0);
    };

    // prologue: X0,A0,X1,A1 in flight; B(step0) staged
    LOADX(0, 0); LOADA(0, 0);
    LOADX(1, 1); LOADA(1, 1);
    PROCB(0, 0);
    asm volatile("s_waitcnt lgkmcnt(0)" ::: "memory");
    __builtin_amdgcn_s_barrier();

    for (int ii = 0; ii < 15; ++ii) {
        const int base = ii << 2;
        #pragma unroll
        for (int S = 0; S < 4; ++S) {
            bf16x8 bfr[4];
            RD_B(S & 1, bfr);
            LOADX(base + S + 2, S & 1);
            LOADA(base + S + 2, (S + 2) & 3);
            MFMA16(S & 3, bfr);
            PROCB((S + 1) & 1, (S + 1) & 1);
            asm volatile("s_waitcnt lgkmcnt(0)" ::: "memory");
            __builtin_amdgcn_s_barrier();
        }
    }
    // tail: steps 60..63
    #pragma unroll
    for (int S = 0; S < 4; ++S) {
        bf16x8 bfr[4];
        RD_B(S & 1, bfr);
        if (S < 2) { LOADX(62 + S, S & 1); LOADA(62 + S, (S + 2) & 3); }
        MFMA16(S & 3, bfr);
        if (S < 3) PROCB((S + 1) & 1, (S + 1) & 1);
        asm volatile("s_waitcnt lgkmcnt(0)" ::: "memory");
        __builtin_amdgcn_s_barrier();
    }

    // ---- column norms from precomputed cnsq ----
    float cns[4];
    #pragma unroll
    for (int nt = 0; nt < 4; ++nt) {
        int col = p0 + (nt << 4) + lr16;
        cns[nt] = (col < P_DIM) ? fmaxf(sqrtf(cnsq[b * P_DIM + col]), 1e-12f) : 1.f;
    }

    // ---- epilogue: tanh + partial k-reduction with wsi ----
    float ssv[4] = {0.f, 0.f, 0.f, 0.f};
    #pragma unroll
    for (int mt = 0; mt < 4; ++mt) {
        int rl = (w << 6) + (mt << 4) + (lh << 2);
        #pragma unroll
        for (int j = 0; j < 4; ++j) {
            int r = Rb + rl + j;
            float wsiv = wsi[r];
            float vb = vv[b * K_DIM + r];
            #pragma unroll
            for (int nt = 0; nt < 4; ++nt) {
                float a = acc[mt][nt][j] / cns[nt] + vb;
                ssv[nt] = fmaf(wsiv, fast_tanh(a), ssv[nt]);
            }
        }
    }
    #pragma unroll
    for (int nt = 0; nt < 4; ++nt) {
        ssv[nt] += __shfl_xor(ssv[nt], 16);
        ssv[nt] += __shfl_xor(ssv[nt], 32);
    }
    if (lh == 0) {
        #pragma unroll
        for (int nt = 0; nt < 4; ++nt) lss[w][(nt << 4) + lr16] = ssv[nt];
    }
    __syncthreads();
    if (t < 64) {
        float s = lss[0][t] + lss[1][t] + lss[2][t] + lss[3][t];
        ssp[((blockIdx.y << 6) + b) * 256 + p0 + t] = s;
    }
}

// ---------------- K6: softmax over P (sums the 2 k-split partials) ----------------
__global__ void k6_softmax_p(const float* __restrict__ ssp, const float* __restrict__ bsi,
                             float* __restrict__ asp) {
    int b = blockIdx.x, t = threadIdx.x;
    __shared__ float red[4], red2[4];
    float val = -1e30f;
    if (t < P_DIM) val = ssp[b * 256 + t] + ssp[(64 + b) * 256 + t] + bsi[0];
    float m = val;
    for (int off = 32; off; off >>= 1) m = fmaxf(m, __shfl_xor(m, off));
    if ((t & 63) == 0) red[t >> 6] = m;
    __syncthreads();
    m = fmaxf(fmaxf(red[0], red[1]), fmaxf(red[2], red[3]));
    float e = (t < P_DIM) ? __expf(val - m) : 0.f;
    float sum = e;
    for (int off = 32; off; off >>= 1) sum += __shfl_xor(sum, off);
    if ((t & 63) == 0) red2[t >> 6] = sum;
    __syncthreads();
    sum = red2[0] + red2[1] + red2[2] + red2[3];
    if (t < P_DIM) asp[b * P_DIM + t] = e / sum;
}

// ---------------- K7: out = xw(bf16) * asp[b,p] ----------------
__global__ void k7_out(const u16* __restrict__ xw, const float* __restrict__ asp,
                       float* __restrict__ out) {
    int idx = blockIdx.x * 256 + threadIdx.x;  // 4-element unit; 196 = 49*4
    int row = idx / 49;                        // b*C + c
    int pq = idx - row * 49;
    int b = row >> 11;
    uint2 xv = *(const uint2*)(xw + (size_t)row * P_DIM + pq * 4);
    float4 pv = *(const float4*)&asp[b * P_DIM + pq * 4];
    float4 o;
    o.x = bf2f((u16)(xv.x & 0xffff)) * pv.x;
    o.y = bf2f((u16)(xv.x >> 16))    * pv.y;
    o.z = bf2f((u16)(xv.y & 0xffff)) * pv.z;
    o.w = bf2f((u16)(xv.y >> 16))    * pv.w;
    ((float4*)out)[idx] = o;
}

extern "C" void kernel_launch(void* const* d_in, const int* in_sizes, int n_in,
                              void* d_out, int out_size, void* d_ws, size_t ws_size,
                              hipStream_t stream) {
    const float* img = (const float*)d_in[0];
    const float* h   = (const float*)d_in[1];
    const float* wc  = (const float*)d_in[2];
    const float* bc  = (const float*)d_in[3];
    const float* whc = (const float*)d_in[4];
    const float* wci = (const float*)d_in[5];
    const float* bci = (const float*)d_in[6];
    const float* ws  = (const float*)d_in[7];
    const float* bs  = (const float*)d_in[8];
    const float* whs = (const float*)d_in[9];
    const float* wsi = (const float*)d_in[10];
    const float* bsi = (const float*)d_in[11];
    float* out = (float*)d_out;

    char* wsp = (char*)d_ws;
    float* ic   = (float*)(wsp);                // 512 KB
    float* u    = (float*)(wsp + 0x080000);     // 128 KB
    float* v    = (float*)(wsp + 0x0A0000);     // 128 KB
    float* sc   = (float*)(wsp + 0x0C0000);     // 512 KB
    float* ac   = (float*)(wsp + 0x140000);     // 512 KB
    float* ssp  = (float*)(wsp + 0x1C0000);     // 128 KB [2][64][256]
    float* asp  = (float*)(wsp + 0x1E0000);     // 50 KB
    float* cnsq = (float*)(wsp + 0x1F0000);     // 50 KB
    u16*   wsb2 = (u16*)  (wsp + 0x200000);     // 2 MB (repacked)
    u16*   xw   = (u16*)  (wsp + 0x400000);     // 51.4 MB bf16 xw

    k1_rowstats<<<dim3(32768), dim3(256), 0, stream>>>(img, ic);
    k2_hproj<<<dim3(512), dim3(256), 0, stream>>>(h, whc, bc, whs, bs, u, v);
    k2b_conv<<<dim3(512), dim3(256), 0, stream>>>(ws, wsb2);
    k3_sc<<<dim3(8, 64), dim3(256), 0, stream>>>(ic, u, wc, wci, bci, sc);
    k4_softmax_c<<<dim3(64), dim3(256), 0, stream>>>(sc, ac, cnsq);
    k_xw<<<dim3(16, 64), dim3(256), 0, stream>>>(img, ac, xw, cnsq);
    k5_gemm<<<dim3(4, 2, 64), dim3(256), 0, stream>>>(xw, wsb2, cnsq, v, wsi, ssp);
    k6_softmax_p<<<dim3(64), dim3(256), 0, stream>>>(ssp, bsi, asp);
    k7_out<<<dim3(25088), dim3(256), 0, stream>>>(xw, asp, out);
}